// Round 10
// baseline (362.215 us; speedup 1.0000x reference)
//
#include <hip/hip_runtime.h>

typedef __attribute__((ext_vector_type(8))) short bf16x8;
typedef __attribute__((ext_vector_type(4))) float f32x4;

__device__ __forceinline__ short f2bf(float f) {
    union { float f; unsigned u; } v; v.f = f;
    unsigned r = (v.u + 0x7FFFu + ((v.u >> 16) & 1u)) >> 16;  // RNE
    return (short)r;
}

__device__ __forceinline__ float bf2f(short s) {
    return __int_as_float(((int)(unsigned short)s) << 16);
}

__device__ __forceinline__ float sigmoidf(float x) {
    return 1.0f / (1.0f + __expf(-x));
}

// DPP butterfly add (VALU pipe). 16-lane sum in every lane.
template<int CTRL>
__device__ __forceinline__ float dpp_add(float v) {
    int x = __builtin_amdgcn_update_dpp(0, __float_as_int(v), CTRL, 0xF, 0xF, true);
    return v + __int_as_float(x);
}
__device__ __forceinline__ float red16(float p) {
    p = dpp_add<0xB1>(p);
    p = dpp_add<0x4E>(p);
    p = dpp_add<0x141>(p);
    p = dpp_add<0x140>(p);
    return p;
}

constexpr int S = 200, E = 128, A = 64;
constexpr int NSTRIP = 13;   // ceil(200/16)

// packed f32->bf16 (RNE): 4 v_cvt_pk_bf16_f32
__device__ __forceinline__ bf16x8 pack8(const f32x4 a, const f32x4 b) {
    union { bf16x8 v; unsigned u[4]; } r;
    asm("v_cvt_pk_bf16_f32 %0, %1, %2" : "=v"(r.u[0]) : "v"(a[0]), "v"(a[1]));
    asm("v_cvt_pk_bf16_f32 %0, %1, %2" : "=v"(r.u[1]) : "v"(a[2]), "v"(a[3]));
    asm("v_cvt_pk_bf16_f32 %0, %1, %2" : "=v"(r.u[2]) : "v"(b[0]), "v"(b[1]));
    asm("v_cvt_pk_bf16_f32 %0, %1, %2" : "=v"(r.u[3]) : "v"(b[2]), "v"(b[3]));
    return r.v;
}

// f32 strip loader (fallback kernel only)
__device__ __forceinline__ void load_strip(f32x4 av[4][2], const float* __restrict__ bptr,
                                           int st, int l15, int quad)
{
    #pragma unroll
    for (int kt = 0; kt < 4; ++kt) {
        av[kt][0] = f32x4{0.f, 0.f, 0.f, 0.f};
        av[kt][1] = f32x4{0.f, 0.f, 0.f, 0.f};
    }
    const int row = st * 16 + l15;
    if (st < NSTRIP && row < S) {
        const float* rp = bptr + (size_t)row * E + quad * 8;
        #pragma unroll
        for (int kt = 0; kt < 4; ++kt) {
            av[kt][0] = __builtin_nontemporal_load((const f32x4*)(rp + kt * 32));
            av[kt][1] = __builtin_nontemporal_load((const f32x4*)(rp + kt * 32 + 4));
        }
    }
}

// bf16 strip loader: nt-load f32, convert once at load. Buffer = 16 VGPR/strip
// (was 32) -> live set ~115 -> 4 waves/SIMD possible without spill.
__device__ __forceinline__ void load_strip16(bf16x8 av[4], const float* __restrict__ bptr,
                                             int st, int l15, int quad)
{
    #pragma unroll
    for (int kt = 0; kt < 4; ++kt)
        av[kt] = bf16x8{0, 0, 0, 0, 0, 0, 0, 0};
    const int row = st * 16 + l15;
    if (st < NSTRIP && row < S) {
        const float* rp = bptr + (size_t)row * E + quad * 8;
        #pragma unroll
        for (int kt = 0; kt < 4; ++kt) {
            f32x4 a = __builtin_nontemporal_load((const f32x4*)(rp + kt * 32));
            f32x4 b = __builtin_nontemporal_load((const f32x4*)(rp + kt * 32 + 4));
            av[kt] = pack8(a, b);
        }
    }
}

// ---------------------------------------------------------------------------
// Prep kernel: per-batch folded weights Wb (frag-linear bf16) + bias beta.
// Wb[e][a] = W1a + W1d + t[e]*W1c ; beta = b1 + t @ (W1b - W1d).
// ---------------------------------------------------------------------------
__global__ __launch_bounds__(256, 4) void attn_prep(
    const float* __restrict__ target,
    const float* __restrict__ W1,
    const float* __restrict__ b1,
    short* __restrict__ wb_all,     // [B][8192] frag-linear bf16
    float* __restrict__ beta_all)   // [B][64]
{
    __shared__ float wtmp[E * 65];   // +1 pad: conflict-free scattered reads
    __shared__ float redp[256];
    __shared__ float t_lds[E];

    const int tid = threadIdx.x;
    const int bat = blockIdx.x;

    if (tid < E) t_lds[tid] = target[(size_t)bat * E + tid];
    __syncthreads();

    for (int i = tid; i < E * A; i += 256) {
        const int e = i >> 6;
        wtmp[e * 65 + (i & 63)] =
            W1[i] + W1[3 * E * A + i] + t_lds[e] * W1[2 * E * A + i];
    }
    {
        const int a = tid & 63, seg = tid >> 6;
        float acc = 0.f;
        #pragma unroll 8
        for (int e = seg * 32; e < seg * 32 + 32; ++e)
            acc += t_lds[e] * (W1[(128 + e) * A + a] - W1[(384 + e) * A + a]);
        redp[seg * 64 + a] = acc;
    }
    __syncthreads();
    if (tid < A)
        beta_all[(size_t)bat * A + tid] =
            b1[tid] + redp[tid] + redp[64 + tid] + redp[128 + tid] + redp[192 + tid];

    short* wbd = wb_all + (size_t)bat * (E * A);
    for (int i = tid; i < E * A; i += 256) {
        const int j = i & 7, ln = (i >> 3) & 63, f = i >> 9;
        const int kt = f >> 2, nt = f & 3;
        const int n = nt * 16 + (ln & 15);
        const int k = kt * 32 + (ln >> 4) * 8 + j;
        wbd[i] = f2bf(wtmp[k * 65 + n]);
    }
}

// ---------------------------------------------------------------------------
// Main streaming kernel, 2 batches per block (grid 1024).
// R9 best (307): (256,2), f32 2-buf strips, pairing, DPP, nt loads.
// This round: bf16 strip buffers (-32 VGPR, live ~115; MFMA input identical,
// PV now uses bf16-rounded behaviors) + amdgpu_waves_per_eu(4,4) (128-VGPR
// budget, hard-clamped both ways per R4's overshoot lesson) -> 16 waves/CU,
// the occupancy experiment R1/R4/R5 could never run without spilling.
// ---------------------------------------------------------------------------
__global__ __launch_bounds__(256)
__attribute__((amdgpu_waves_per_eu(4, 4)))
void attn_main(
    const float* __restrict__ behaviors,
    const float* __restrict__ W2,
    const float* __restrict__ b2,
    const short* __restrict__ wb_all,
    const float* __restrict__ beta_all,
    float* __restrict__ out)
{
    __shared__ short wb_f[16 * 512];   // 16 KB frag-linear bf16 Wb
    __shared__ float red[4 * 128];     // 2 KB final reduction
    __shared__ float bias_lds[A];
    __shared__ float w2_lds[A];

    const int tid  = threadIdx.x;
    const int lane = tid & 63;
    const int wave = tid >> 6;
    const int l15  = lane & 15;
    const int quad = lane >> 4;

    const int bstride = gridDim.x;      // 1024
    int bat = blockIdx.x;

    const float* bptr = behaviors + (size_t)bat * S * E;

    // issue BOTH strip buffers' global loads before anything else
    bf16x8 avA[4], avB[4];
    load_strip16(avA, bptr, wave, l15, quad);
    load_strip16(avB, bptr, wave + 4, l15, quad);

    // coalesced 16 KB Wb copy (read-once stream: non-temporal)
    {
        const f32x4* wsrc = (const f32x4*)(wb_all + (size_t)bat * (E * A));
        #pragma unroll
        for (int i = 0; i < 4; ++i)
            *(f32x4*)&wb_f[(tid + i * 256) * 8] =
                __builtin_nontemporal_load(&wsrc[tid + i * 256]);
    }
    if (tid < A) {
        bias_lds[tid] = beta_all[(size_t)bat * A + tid];
        w2_lds[tid]   = W2[tid];
    }
    __syncthreads();

    const float b2v = b2[0];

    #pragma unroll 1
    for (int bi = 0; bi < 2; ++bi) {
        float bias_l[4], w2_l[4];
        #pragma unroll
        for (int nt = 0; nt < 4; ++nt) {
            bias_l[nt] = bias_lds[nt * 16 + l15];
            w2_l[nt]   = w2_lds[nt * 16 + l15];
        }

        f32x4 oacc[4][2];
        #pragma unroll
        for (int kt = 0; kt < 4; ++kt) {
            oacc[kt][0] = f32x4{0.f, 0.f, 0.f, 0.f};
            oacc[kt][1] = f32x4{0.f, 0.f, 0.f, 0.f};
        }

        #pragma unroll
        for (int it = 0; it < 4; ++it) {
            const int st = wave + it * 4;
            if (st >= NSTRIP) break;
            bf16x8* cur = (it & 1) ? avB : avA;

            f32x4 acc[4];
            #pragma unroll
            for (int nt = 0; nt < 4; ++nt) acc[nt] = f32x4{0.f, 0.f, 0.f, 0.f};

            #pragma unroll
            for (int kt = 0; kt < 4; ++kt) {
                const bf16x8 af = cur[kt];   // already bf16: no per-iter cvt
                #pragma unroll
                for (int nt = 0; nt < 4; ++nt) {
                    bf16x8 bf1 = *(const bf16x8*)&wb_f[(kt * 4 + nt) * 512 + lane * 8];
                    acc[nt] = __builtin_amdgcn_mfma_f32_16x16x32_bf16(af, bf1, acc[nt], 0, 0, 0);
                }
            }

            // logits: C row = quad*4+reg, col = nt*16+l15; reduce over 16 a-lanes
            float wgt[4];
            #pragma unroll
            for (int reg = 0; reg < 4; ++reg) {
                float p = 0.f;
                #pragma unroll
                for (int nt = 0; nt < 4; ++nt) {
                    const float h = acc[nt][reg] + bias_l[nt];
                    p += fmaxf(h, 0.f) * w2_l[nt];
                }
                p = red16(p);          // DPP butterfly (VALU)
                wgt[reg] = sigmoidf(p + b2v);
            }

            const int srcl = (l15 >> 2) << 4;
            const float t0 = __shfl(wgt[0], srcl, 64);
            const float t1 = __shfl(wgt[1], srcl, 64);
            const float t2 = __shfl(wgt[2], srcl, 64);
            const float t3 = __shfl(wgt[3], srcl, 64);
            const float wl = (l15 & 2) ? ((l15 & 1) ? t3 : t2)
                                       : ((l15 & 1) ? t1 : t0);

            #pragma unroll
            for (int kt = 0; kt < 4; ++kt)
                #pragma unroll
                for (int j = 0; j < 8; ++j)
                    oacc[kt][j >> 2][j & 3] += wl * bf2f(cur[kt][j]);

            // prefetch strip st+8 into the buffer we just finished consuming
            if (st + 8 < NSTRIP) load_strip16(cur, bptr, st + 8, l15, quad);
        }

        // ---- batch transition: issue next batch's loads NOW (buffers dead);
        // the register-only epilogue below covers their latency.
        const int nbat = bat + bstride;
        const float* nbptr = behaviors + (size_t)nbat * S * E;
        f32x4 wbr[4];
        float betar = 0.f;
        if (bi == 0) {
            load_strip16(avA, nbptr, wave, l15, quad);
            load_strip16(avB, nbptr, wave + 4, l15, quad);
            const f32x4* wsrc = (const f32x4*)(wb_all + (size_t)nbat * (E * A));
            #pragma unroll
            for (int i = 0; i < 4; ++i)
                wbr[i] = __builtin_nontemporal_load(&wsrc[tid + i * 256]);
            if (tid < A) betar = beta_all[(size_t)nbat * A + tid];
        }

        // epilogue: reduce oacc over the 16 rows (l15 lanes) of each quad
        #pragma unroll
        for (int kt = 0; kt < 4; ++kt)
            #pragma unroll
            for (int h = 0; h < 2; ++h)
                #pragma unroll
                for (int c = 0; c < 4; ++c)
                    oacc[kt][h][c] = red16(oacc[kt][h][c]);

        if (l15 == 0) {
            #pragma unroll
            for (int kt = 0; kt < 4; ++kt) {
                *(f32x4*)&red[wave * 128 + kt * 32 + quad * 8]     = oacc[kt][0];
                *(f32x4*)&red[wave * 128 + kt * 32 + quad * 8 + 4] = oacc[kt][1];
            }
        }
        __syncthreads();   // all waves past MFMAs (wb_f free) and red written
        if (tid < E) {
            const float ov = red[tid] + red[128 + tid] + red[256 + tid] + red[384 + tid];
            __builtin_nontemporal_store(ov, &out[(size_t)bat * E + tid]);
        }

        if (bi == 0) {
            // install next batch's weights (loads issued before epilogue)
            #pragma unroll
            for (int i = 0; i < 4; ++i)
                *(f32x4*)&wb_f[(tid + i * 256) * 8] = wbr[i];
            if (tid < A) bias_lds[tid] = betar;
            __syncthreads();
            bat = nbat;
            bptr = nbptr;
        }
    }
}

// ---------------------------------------------------------------------------
// Fallback: single-kernel version (used only if ws too small).
// ---------------------------------------------------------------------------
__global__ __launch_bounds__(256, 2) void attn_fused_fb(
    const float* __restrict__ behaviors,
    const float* __restrict__ target,
    const float* __restrict__ W1,
    const float* __restrict__ b1,
    const float* __restrict__ W2,
    const float* __restrict__ b2,
    float* __restrict__ out)
{
    __shared__ short wb_f[16 * 512];
    __shared__ short wbtmp[E * A];
    __shared__ float red[4 * 128];
    __shared__ float t_lds[E];
    __shared__ float bias_lds[A];
    __shared__ float w2_lds[A];

    const int tid  = threadIdx.x;
    const int bat  = blockIdx.x;
    const int lane = tid & 63;
    const int wave = tid >> 6;
    const int l15  = lane & 15;
    const int quad = lane >> 4;

    const float* bptr = behaviors + (size_t)bat * S * E;

    f32x4 avA[4][2], avB[4][2];
    load_strip(avA, bptr, wave, l15, quad);

    if (tid < E) t_lds[tid] = target[(size_t)bat * E + tid];
    __syncthreads();

    for (int i = tid; i < E * A; i += 256) {
        const int e = i >> 6, a = i & 63;
        wbtmp[i] = f2bf(W1[e * A + a] + W1[(384 + e) * A + a]
                        + t_lds[e] * W1[(256 + e) * A + a]);
    }
    {
        const int a = tid & 63, seg = tid >> 6;
        float acc = 0.f;
        #pragma unroll 8
        for (int e = seg * 32; e < seg * 32 + 32; ++e)
            acc += t_lds[e] * (W1[(128 + e) * A + a] - W1[(384 + e) * A + a]);
        red[seg * 64 + a] = acc;
    }
    __syncthreads();
    if (tid < A) {
        bias_lds[tid] = b1[tid] + red[tid] + red[64 + tid] + red[128 + tid] + red[192 + tid];
        w2_lds[tid] = W2[tid];
    }
    for (int i = tid; i < E * A; i += 256) {
        const int j = i & 7, ln = (i >> 3) & 63, f = i >> 9;
        const int kt = f >> 2, nt = f & 3;
        const int n = nt * 16 + (ln & 15);
        const int k = kt * 32 + (ln >> 4) * 8 + j;
        wb_f[i] = wbtmp[k * A + n];
    }
    __syncthreads();

    float bias_l[4], w2_l[4];
    #pragma unroll
    for (int nt = 0; nt < 4; ++nt) {
        bias_l[nt] = bias_lds[nt * 16 + l15];
        w2_l[nt]   = w2_lds[nt * 16 + l15];
    }
    const float b2v = b2[0];

    f32x4 oacc[4][2];
    #pragma unroll
    for (int kt = 0; kt < 4; ++kt) {
        oacc[kt][0] = f32x4{0.f, 0.f, 0.f, 0.f};
        oacc[kt][1] = f32x4{0.f, 0.f, 0.f, 0.f};
    }

    #pragma unroll
    for (int it = 0; it < 4; ++it) {
        const int st = wave + it * 4;
        if (st >= NSTRIP) break;
        f32x4 (*cur)[2] = (it & 1) ? avB : avA;
        f32x4 (*nxt)[2] = (it & 1) ? avA : avB;
        load_strip(nxt, bptr, st + 4, l15, quad);

        f32x4 acc[4];
        #pragma unroll
        for (int nt = 0; nt < 4; ++nt) acc[nt] = f32x4{0.f, 0.f, 0.f, 0.f};

        #pragma unroll
        for (int kt = 0; kt < 4; ++kt) {
            const bf16x8 af = pack8(cur[kt][0], cur[kt][1]);
            #pragma unroll
            for (int nt = 0; nt < 4; ++nt) {
                bf16x8 bf1 = *(const bf16x8*)&wb_f[(kt * 4 + nt) * 512 + lane * 8];
                acc[nt] = __builtin_amdgcn_mfma_f32_16x16x32_bf16(af, bf1, acc[nt], 0, 0, 0);
            }
        }

        float wgt[4];
        #pragma unroll
        for (int reg = 0; reg < 4; ++reg) {
            float p = 0.f;
            #pragma unroll
            for (int nt = 0; nt < 4; ++nt) {
                const float h = acc[nt][reg] + bias_l[nt];
                p += fmaxf(h, 0.f) * w2_l[nt];
            }
            p = red16(p);
            wgt[reg] = sigmoidf(p + b2v);
        }

        const int srcl = (l15 >> 2) << 4;
        const float t0 = __shfl(wgt[0], srcl, 64);
        const float t1 = __shfl(wgt[1], srcl, 64);
        const float t2 = __shfl(wgt[2], srcl, 64);
        const float t3 = __shfl(wgt[3], srcl, 64);
        const float wl = (l15 & 2) ? ((l15 & 1) ? t3 : t2)
                                   : ((l15 & 1) ? t1 : t0);

        #pragma unroll
        for (int kt = 0; kt < 4; ++kt)
            #pragma unroll
            for (int h = 0; h < 2; ++h) {
                oacc[kt][h][0] += wl * cur[kt][h][0];
                oacc[kt][h][1] += wl * cur[kt][h][1];
                oacc[kt][h][2] += wl * cur[kt][h][2];
                oacc[kt][h][3] += wl * cur[kt][h][3];
            }
    }

    #pragma unroll
    for (int kt = 0; kt < 4; ++kt)
        #pragma unroll
        for (int h = 0; h < 2; ++h)
            #pragma unroll
            for (int c = 0; c < 4; ++c)
                oacc[kt][h][c] = red16(oacc[kt][h][c]);

    if (l15 == 0) {
        #pragma unroll
        for (int kt = 0; kt < 4; ++kt) {
            *(f32x4*)&red[wave * 128 + kt * 32 + quad * 8]     = oacc[kt][0];
            *(f32x4*)&red[wave * 128 + kt * 32 + quad * 8 + 4] = oacc[kt][1];
        }
    }
    __syncthreads();
    if (tid < E) {
        out[(size_t)bat * E + tid] =
            red[tid] + red[128 + tid] + red[256 + tid] + red[384 + tid];
    }
}

extern "C" void kernel_launch(void* const* d_in, const int* in_sizes, int n_in,
                              void* d_out, int out_size, void* d_ws, size_t ws_size,
                              hipStream_t stream) {
    const float* behaviors = (const float*)d_in[0];
    const float* target    = (const float*)d_in[1];
    const float* W1        = (const float*)d_in[2];
    const float* b1        = (const float*)d_in[3];
    const float* W2        = (const float*)d_in[4];
    const float* b2        = (const float*)d_in[5];
    float* out = (float*)d_out;

    const size_t wb_bytes   = (size_t)2048 * (E * A) * sizeof(short);
    const size_t beta_bytes = (size_t)2048 * A * sizeof(float);

    if (d_ws && ws_size >= wb_bytes + beta_bytes) {
        short* wb_all   = (short*)d_ws;
        float* beta_all = (float*)((char*)d_ws + wb_bytes);
        hipLaunchKernelGGL(attn_prep, dim3(2048), dim3(256), 0, stream,
                           target, W1, b1, wb_all, beta_all);
        hipLaunchKernelGGL(attn_main, dim3(1024), dim3(256), 0, stream,
                           behaviors, W2, b2, wb_all, beta_all, out);
    } else {
        hipLaunchKernelGGL(attn_fused_fb, dim3(2048), dim3(256), 0, stream,
                           behaviors, target, W1, b1, W2, b2, out);
    }
}

// Round 11
// 306.331 us; speedup vs baseline: 1.1824x; 1.1824x over previous
//
#include <hip/hip_runtime.h>

typedef __attribute__((ext_vector_type(8))) short bf16x8;
typedef __attribute__((ext_vector_type(4))) float f32x4;

__device__ __forceinline__ short f2bf(float f) {
    union { float f; unsigned u; } v; v.f = f;
    unsigned r = (v.u + 0x7FFFu + ((v.u >> 16) & 1u)) >> 16;  // RNE
    return (short)r;
}

__device__ __forceinline__ float sigmoidf(float x) {
    return 1.0f / (1.0f + __expf(-x));
}

// DPP butterfly add (VALU pipe). 16-lane sum in every lane.
template<int CTRL>
__device__ __forceinline__ float dpp_add(float v) {
    int x = __builtin_amdgcn_update_dpp(0, __float_as_int(v), CTRL, 0xF, 0xF, true);
    return v + __int_as_float(x);
}
__device__ __forceinline__ float red16(float p) {
    p = dpp_add<0xB1>(p);
    p = dpp_add<0x4E>(p);
    p = dpp_add<0x141>(p);
    p = dpp_add<0x140>(p);
    return p;
}

constexpr int S = 200, E = 128, A = 64;
constexpr int NSTRIP = 13;   // ceil(200/16)

// behaviors is read exactly once (zero reuse): non-temporal loads bypass
// L1/L2 allocation -> pure read stream, no eviction churn. (R9: -10 us)
__device__ __forceinline__ void load_strip(f32x4 av[4][2], const float* __restrict__ bptr,
                                           int st, int l15, int quad)
{
    #pragma unroll
    for (int kt = 0; kt < 4; ++kt) {
        av[kt][0] = f32x4{0.f, 0.f, 0.f, 0.f};
        av[kt][1] = f32x4{0.f, 0.f, 0.f, 0.f};
    }
    const int row = st * 16 + l15;
    if (st < NSTRIP && row < S) {
        const float* rp = bptr + (size_t)row * E + quad * 8;
        #pragma unroll
        for (int kt = 0; kt < 4; ++kt) {
            av[kt][0] = __builtin_nontemporal_load((const f32x4*)(rp + kt * 32));
            av[kt][1] = __builtin_nontemporal_load((const f32x4*)(rp + kt * 32 + 4));
        }
    }
}

// packed f32->bf16 (RNE): 4 v_cvt_pk_bf16_f32
__device__ __forceinline__ bf16x8 pack8(const f32x4 a, const f32x4 b) {
    union { bf16x8 v; unsigned u[4]; } r;
    asm("v_cvt_pk_bf16_f32 %0, %1, %2" : "=v"(r.u[0]) : "v"(a[0]), "v"(a[1]));
    asm("v_cvt_pk_bf16_f32 %0, %1, %2" : "=v"(r.u[1]) : "v"(a[2]), "v"(a[3]));
    asm("v_cvt_pk_bf16_f32 %0, %1, %2" : "=v"(r.u[2]) : "v"(b[0]), "v"(b[1]));
    asm("v_cvt_pk_bf16_f32 %0, %1, %2" : "=v"(r.u[3]) : "v"(b[2]), "v"(b[3]));
    return r.v;
}

// ---------------------------------------------------------------------------
// Prep kernel: per-batch folded weights Wb (frag-linear bf16) + bias beta.
// Wb[e][a] = W1a + W1d + t[e]*W1c ; beta = b1 + t @ (W1b - W1d).
// ---------------------------------------------------------------------------
__global__ __launch_bounds__(256, 4) void attn_prep(
    const float* __restrict__ target,
    const float* __restrict__ W1,
    const float* __restrict__ b1,
    short* __restrict__ wb_all,     // [B][8192] frag-linear bf16
    float* __restrict__ beta_all)   // [B][64]
{
    __shared__ float wtmp[E * 65];   // +1 pad: conflict-free scattered reads
    __shared__ float redp[256];
    __shared__ float t_lds[E];

    const int tid = threadIdx.x;
    const int bat = blockIdx.x;

    if (tid < E) t_lds[tid] = target[(size_t)bat * E + tid];
    __syncthreads();

    for (int i = tid; i < E * A; i += 256) {
        const int e = i >> 6;
        wtmp[e * 65 + (i & 63)] =
            W1[i] + W1[3 * E * A + i] + t_lds[e] * W1[2 * E * A + i];
    }
    {
        const int a = tid & 63, seg = tid >> 6;
        float acc = 0.f;
        #pragma unroll 8
        for (int e = seg * 32; e < seg * 32 + 32; ++e)
            acc += t_lds[e] * (W1[(128 + e) * A + a] - W1[(384 + e) * A + a]);
        redp[seg * 64 + a] = acc;
    }
    __syncthreads();
    if (tid < A)
        beta_all[(size_t)bat * A + tid] =
            b1[tid] + redp[tid] + redp[64 + tid] + redp[128 + tid] + redp[192 + tid];

    short* wbd = wb_all + (size_t)bat * (E * A);
    for (int i = tid; i < E * A; i += 256) {
        const int j = i & 7, ln = (i >> 3) & 63, f = i >> 9;
        const int kt = f >> 2, nt = f & 3;
        const int n = nt * 16 + (ln & 15);
        const int k = kt * 32 + (ln >> 4) * 8 + j;
        wbd[i] = f2bf(wtmp[k * 65 + n]);
    }
}

// ---------------------------------------------------------------------------
// Main streaming kernel, 2 batches per block (grid 1024).
// EXACT round-9 configuration (session best, 307.0 graded):
// (256,2), f32 2-buf strips, batch-pairing, DPP reductions, nt loads/stores.
// Register-allocation record: every occupancy-steering attempt spilled or
// regressed (R1 min4: 368; R4 min3: 334; R5 clamp33: 334; R10 bf16+clamp44:
// VGPR=64 + 161MB spill, 362). (256,2) is the single healthy alloc point.
// ---------------------------------------------------------------------------
__global__ __launch_bounds__(256, 2) void attn_main(
    const float* __restrict__ behaviors,
    const float* __restrict__ W2,
    const float* __restrict__ b2,
    const short* __restrict__ wb_all,
    const float* __restrict__ beta_all,
    float* __restrict__ out)
{
    __shared__ short wb_f[16 * 512];   // 16 KB frag-linear bf16 Wb
    __shared__ float red[4 * 128];     // 2 KB final reduction
    __shared__ float bias_lds[A];
    __shared__ float w2_lds[A];

    const int tid  = threadIdx.x;
    const int lane = tid & 63;
    const int wave = tid >> 6;
    const int l15  = lane & 15;
    const int quad = lane >> 4;

    const int bstride = gridDim.x;      // 1024
    int bat = blockIdx.x;

    const float* bptr = behaviors + (size_t)bat * S * E;

    // issue BOTH strip buffers' global loads before anything else
    f32x4 avA[4][2], avB[4][2];
    load_strip(avA, bptr, wave, l15, quad);
    load_strip(avB, bptr, wave + 4, l15, quad);

    // coalesced 16 KB Wb copy (read-once stream: non-temporal)
    {
        const f32x4* wsrc = (const f32x4*)(wb_all + (size_t)bat * (E * A));
        #pragma unroll
        for (int i = 0; i < 4; ++i)
            *(f32x4*)&wb_f[(tid + i * 256) * 8] =
                __builtin_nontemporal_load(&wsrc[tid + i * 256]);
    }
    if (tid < A) {
        bias_lds[tid] = beta_all[(size_t)bat * A + tid];
        w2_lds[tid]   = W2[tid];
    }
    __syncthreads();

    const float b2v = b2[0];

    #pragma unroll 1
    for (int bi = 0; bi < 2; ++bi) {
        float bias_l[4], w2_l[4];
        #pragma unroll
        for (int nt = 0; nt < 4; ++nt) {
            bias_l[nt] = bias_lds[nt * 16 + l15];
            w2_l[nt]   = w2_lds[nt * 16 + l15];
        }

        f32x4 oacc[4][2];
        #pragma unroll
        for (int kt = 0; kt < 4; ++kt) {
            oacc[kt][0] = f32x4{0.f, 0.f, 0.f, 0.f};
            oacc[kt][1] = f32x4{0.f, 0.f, 0.f, 0.f};
        }

        #pragma unroll
        for (int it = 0; it < 4; ++it) {
            const int st = wave + it * 4;
            if (st >= NSTRIP) break;
            f32x4 (*cur)[2] = (it & 1) ? avB : avA;

            f32x4 acc[4];
            #pragma unroll
            for (int nt = 0; nt < 4; ++nt) acc[nt] = f32x4{0.f, 0.f, 0.f, 0.f};

            #pragma unroll
            for (int kt = 0; kt < 4; ++kt) {
                const bf16x8 af = pack8(cur[kt][0], cur[kt][1]);
                #pragma unroll
                for (int nt = 0; nt < 4; ++nt) {
                    bf16x8 bf1 = *(const bf16x8*)&wb_f[(kt * 4 + nt) * 512 + lane * 8];
                    acc[nt] = __builtin_amdgcn_mfma_f32_16x16x32_bf16(af, bf1, acc[nt], 0, 0, 0);
                }
            }

            // logits: C row = quad*4+reg, col = nt*16+l15; reduce over 16 a-lanes
            float wgt[4];
            #pragma unroll
            for (int reg = 0; reg < 4; ++reg) {
                float p = 0.f;
                #pragma unroll
                for (int nt = 0; nt < 4; ++nt) {
                    const float h = acc[nt][reg] + bias_l[nt];
                    p += fmaxf(h, 0.f) * w2_l[nt];
                }
                p = red16(p);          // DPP butterfly (VALU)
                wgt[reg] = sigmoidf(p + b2v);
            }

            const int srcl = (l15 >> 2) << 4;
            const float t0 = __shfl(wgt[0], srcl, 64);
            const float t1 = __shfl(wgt[1], srcl, 64);
            const float t2 = __shfl(wgt[2], srcl, 64);
            const float t3 = __shfl(wgt[3], srcl, 64);
            const float wl = (l15 & 2) ? ((l15 & 1) ? t3 : t2)
                                       : ((l15 & 1) ? t1 : t0);

            #pragma unroll
            for (int kt = 0; kt < 4; ++kt)
                #pragma unroll
                for (int h = 0; h < 2; ++h) {
                    oacc[kt][h][0] += wl * cur[kt][h][0];
                    oacc[kt][h][1] += wl * cur[kt][h][1];
                    oacc[kt][h][2] += wl * cur[kt][h][2];
                    oacc[kt][h][3] += wl * cur[kt][h][3];
                }

            // prefetch strip st+8 into the buffer we just finished consuming
            if (st + 8 < NSTRIP) load_strip(cur, bptr, st + 8, l15, quad);
        }

        // ---- batch transition: issue next batch's loads NOW (buffers dead);
        // the register-only epilogue below covers their latency.
        const int nbat = bat + bstride;
        const float* nbptr = behaviors + (size_t)nbat * S * E;
        f32x4 wbr[4];
        float betar = 0.f;
        if (bi == 0) {
            load_strip(avA, nbptr, wave, l15, quad);
            load_strip(avB, nbptr, wave + 4, l15, quad);
            const f32x4* wsrc = (const f32x4*)(wb_all + (size_t)nbat * (E * A));
            #pragma unroll
            for (int i = 0; i < 4; ++i)
                wbr[i] = __builtin_nontemporal_load(&wsrc[tid + i * 256]);
            if (tid < A) betar = beta_all[(size_t)nbat * A + tid];
        }

        // epilogue: reduce oacc over the 16 rows (l15 lanes) of each quad
        #pragma unroll
        for (int kt = 0; kt < 4; ++kt)
            #pragma unroll
            for (int h = 0; h < 2; ++h)
                #pragma unroll
                for (int c = 0; c < 4; ++c)
                    oacc[kt][h][c] = red16(oacc[kt][h][c]);

        if (l15 == 0) {
            #pragma unroll
            for (int kt = 0; kt < 4; ++kt) {
                *(f32x4*)&red[wave * 128 + kt * 32 + quad * 8]     = oacc[kt][0];
                *(f32x4*)&red[wave * 128 + kt * 32 + quad * 8 + 4] = oacc[kt][1];
            }
        }
        __syncthreads();   // all waves past MFMAs (wb_f free) and red written
        if (tid < E) {
            const float ov = red[tid] + red[128 + tid] + red[256 + tid] + red[384 + tid];
            __builtin_nontemporal_store(ov, &out[(size_t)bat * E + tid]);
        }

        if (bi == 0) {
            // install next batch's weights (loads issued before epilogue)
            #pragma unroll
            for (int i = 0; i < 4; ++i)
                *(f32x4*)&wb_f[(tid + i * 256) * 8] = wbr[i];
            if (tid < A) bias_lds[tid] = betar;
            __syncthreads();
            bat = nbat;
            bptr = nbptr;
        }
    }
}

// ---------------------------------------------------------------------------
// Fallback: single-kernel version (used only if ws too small).
// ---------------------------------------------------------------------------
__global__ __launch_bounds__(256, 2) void attn_fused_fb(
    const float* __restrict__ behaviors,
    const float* __restrict__ target,
    const float* __restrict__ W1,
    const float* __restrict__ b1,
    const float* __restrict__ W2,
    const float* __restrict__ b2,
    float* __restrict__ out)
{
    __shared__ short wb_f[16 * 512];
    __shared__ short wbtmp[E * A];
    __shared__ float red[4 * 128];
    __shared__ float t_lds[E];
    __shared__ float bias_lds[A];
    __shared__ float w2_lds[A];

    const int tid  = threadIdx.x;
    const int bat  = blockIdx.x;
    const int lane = tid & 63;
    const int wave = tid >> 6;
    const int l15  = lane & 15;
    const int quad = lane >> 4;

    const float* bptr = behaviors + (size_t)bat * S * E;

    f32x4 avA[4][2], avB[4][2];
    load_strip(avA, bptr, wave, l15, quad);

    if (tid < E) t_lds[tid] = target[(size_t)bat * E + tid];
    __syncthreads();

    for (int i = tid; i < E * A; i += 256) {
        const int e = i >> 6, a = i & 63;
        wbtmp[i] = f2bf(W1[e * A + a] + W1[(384 + e) * A + a]
                        + t_lds[e] * W1[(256 + e) * A + a]);
    }
    {
        const int a = tid & 63, seg = tid >> 6;
        float acc = 0.f;
        #pragma unroll 8
        for (int e = seg * 32; e < seg * 32 + 32; ++e)
            acc += t_lds[e] * (W1[(128 + e) * A + a] - W1[(384 + e) * A + a]);
        red[seg * 64 + a] = acc;
    }
    __syncthreads();
    if (tid < A) {
        bias_lds[tid] = b1[tid] + red[tid] + red[64 + tid] + red[128 + tid] + red[192 + tid];
        w2_lds[tid] = W2[tid];
    }
    for (int i = tid; i < E * A; i += 256) {
        const int j = i & 7, ln = (i >> 3) & 63, f = i >> 9;
        const int kt = f >> 2, nt = f & 3;
        const int n = nt * 16 + (ln & 15);
        const int k = kt * 32 + (ln >> 4) * 8 + j;
        wb_f[i] = wbtmp[k * A + n];
    }
    __syncthreads();

    float bias_l[4], w2_l[4];
    #pragma unroll
    for (int nt = 0; nt < 4; ++nt) {
        bias_l[nt] = bias_lds[nt * 16 + l15];
        w2_l[nt]   = w2_lds[nt * 16 + l15];
    }
    const float b2v = b2[0];

    f32x4 oacc[4][2];
    #pragma unroll
    for (int kt = 0; kt < 4; ++kt) {
        oacc[kt][0] = f32x4{0.f, 0.f, 0.f, 0.f};
        oacc[kt][1] = f32x4{0.f, 0.f, 0.f, 0.f};
    }

    #pragma unroll
    for (int it = 0; it < 4; ++it) {
        const int st = wave + it * 4;
        if (st >= NSTRIP) break;
        f32x4 (*cur)[2] = (it & 1) ? avB : avA;
        f32x4 (*nxt)[2] = (it & 1) ? avA : avB;
        load_strip(nxt, bptr, st + 4, l15, quad);

        f32x4 acc[4];
        #pragma unroll
        for (int nt = 0; nt < 4; ++nt) acc[nt] = f32x4{0.f, 0.f, 0.f, 0.f};

        #pragma unroll
        for (int kt = 0; kt < 4; ++kt) {
            const bf16x8 af = pack8(cur[kt][0], cur[kt][1]);
            #pragma unroll
            for (int nt = 0; nt < 4; ++nt) {
                bf16x8 bf1 = *(const bf16x8*)&wb_f[(kt * 4 + nt) * 512 + lane * 8];
                acc[nt] = __builtin_amdgcn_mfma_f32_16x16x32_bf16(af, bf1, acc[nt], 0, 0, 0);
            }
        }

        float wgt[4];
        #pragma unroll
        for (int reg = 0; reg < 4; ++reg) {
            float p = 0.f;
            #pragma unroll
            for (int nt = 0; nt < 4; ++nt) {
                const float h = acc[nt][reg] + bias_l[nt];
                p += fmaxf(h, 0.f) * w2_l[nt];
            }
            p = red16(p);
            wgt[reg] = sigmoidf(p + b2v);
        }

        const int srcl = (l15 >> 2) << 4;
        const float t0 = __shfl(wgt[0], srcl, 64);
        const float t1 = __shfl(wgt[1], srcl, 64);
        const float t2 = __shfl(wgt[2], srcl, 64);
        const float t3 = __shfl(wgt[3], srcl, 64);
        const float wl = (l15 & 2) ? ((l15 & 1) ? t3 : t2)
                                   : ((l15 & 1) ? t1 : t0);

        #pragma unroll
        for (int kt = 0; kt < 4; ++kt)
            #pragma unroll
            for (int h = 0; h < 2; ++h) {
                oacc[kt][h][0] += wl * cur[kt][h][0];
                oacc[kt][h][1] += wl * cur[kt][h][1];
                oacc[kt][h][2] += wl * cur[kt][h][2];
                oacc[kt][h][3] += wl * cur[kt][h][3];
            }
    }

    #pragma unroll
    for (int kt = 0; kt < 4; ++kt)
        #pragma unroll
        for (int h = 0; h < 2; ++h)
            #pragma unroll
            for (int c = 0; c < 4; ++c)
                oacc[kt][h][c] = red16(oacc[kt][h][c]);

    if (l15 == 0) {
        #pragma unroll
        for (int kt = 0; kt < 4; ++kt) {
            *(f32x4*)&red[wave * 128 + kt * 32 + quad * 8]     = oacc[kt][0];
            *(f32x4*)&red[wave * 128 + kt * 32 + quad * 8 + 4] = oacc[kt][1];
        }
    }
    __syncthreads();
    if (tid < E) {
        out[(size_t)bat * E + tid] =
            red[tid] + red[128 + tid] + red[256 + tid] + red[384 + tid];
    }
}

extern "C" void kernel_launch(void* const* d_in, const int* in_sizes, int n_in,
                              void* d_out, int out_size, void* d_ws, size_t ws_size,
                              hipStream_t stream) {
    const float* behaviors = (const float*)d_in[0];
    const float* target    = (const float*)d_in[1];
    const float* W1        = (const float*)d_in[2];
    const float* b1        = (const float*)d_in[3];
    const float* W2        = (const float*)d_in[4];
    const float* b2        = (const float*)d_in[5];
    float* out = (float*)d_out;

    const size_t wb_bytes   = (size_t)2048 * (E * A) * sizeof(short);
    const size_t beta_bytes = (size_t)2048 * A * sizeof(float);

    if (d_ws && ws_size >= wb_bytes + beta_bytes) {
        short* wb_all   = (short*)d_ws;
        float* beta_all = (float*)((char*)d_ws + wb_bytes);
        hipLaunchKernelGGL(attn_prep, dim3(2048), dim3(256), 0, stream,
                           target, W1, b1, wb_all, beta_all);
        hipLaunchKernelGGL(attn_main, dim3(1024), dim3(256), 0, stream,
                           behaviors, W2, b2, wb_all, beta_all, out);
    } else {
        hipLaunchKernelGGL(attn_fused_fb, dim3(2048), dim3(256), 0, stream,
                           behaviors, target, W1, b1, W2, b2, out);
    }
}